// Round 18
// baseline (165.558 us; speedup 1.0000x reference)
//
#include <hip/hip_runtime.h>
#include <hip/hip_fp16.h>
#include <math.h>

#define BB 128
#define FF 256
#define NN 2000
#define SWA 16    // stripes per batch (attn AND logits)
#define SCA 128   // cols per stripe
// xh tiled layout: xh_t[b][st][f][c], c in [0,128), cols padded to 2048 (pad zeroed)

typedef float f32x4 __attribute__((ext_vector_type(4)));
union H8 { f32x4 v; __half2 h[4]; };

__device__ __forceinline__ float sel8(f32x4 a, f32x4 b, int e) {
    float v;
    switch (e) {
        case 0: v = a.x; break; case 1: v = a.y; break;
        case 2: v = a.z; break; case 3: v = a.w; break;
        case 4: v = b.x; break; case 5: v = b.y; break;
        case 6: v = b.z; break; default: v = b.w; break;
    }
    return v;
}

__device__ __forceinline__ float dot4(f32x4 a, f32x4 b) {
    float s = a.x * b.x;
    s = fmaf(a.y, b.y, s);
    s = fmaf(a.z, b.z, s);
    s = fmaf(a.w, b.w, s);
    return s;
}

// -------- K1: x -> fp16 (stripe-tiled), row max, lc-gather; 2 rows/wave --------
__global__ __launch_bounds__(256) void k_convmax(const float* __restrict__ x,
                                                 const int* __restrict__ lc,
                                                 __half* __restrict__ xh,
                                                 float* __restrict__ glb,
                                                 float* __restrict__ xg) {
    int w    = threadIdx.x >> 6;
    int lane = threadIdx.x & 63;
    int row0 = (blockIdx.x << 3) + (w << 1);     // 4096 blocks x 4 waves x 2 rows
    int b    = row0 >> 8;
    int f0   = row0 & 255;
    const int c0 = lc[2 * b], c1 = lc[2 * b + 1];
    const int i0 = c0 >> 3, e0 = c0 & 7;
    const int i1 = c1 >> 3, e1 = c1 & 7;
    const f32x4* src0 = (const f32x4*)(x + (size_t)row0 * NN);
    const f32x4* src1 = (const f32x4*)(x + (size_t)(row0 + 1) * NN);
    __half* trow0 = xh + ((size_t)(b << 4) * 256 + f0) * 128;   // + st*32768 + c
    __half* trow1 = trow0 + 128;
    float m0 = -INFINITY, m1 = -INFINITY;
    for (int i = lane; i < 250; i += 64) {
        f32x4 a0 = __builtin_nontemporal_load(src0 + 2 * i);
        f32x4 q0 = __builtin_nontemporal_load(src0 + 2 * i + 1);
        f32x4 a1 = __builtin_nontemporal_load(src1 + 2 * i);
        f32x4 q1 = __builtin_nontemporal_load(src1 + 2 * i + 1);
        m0 = fmaxf(m0, fmaxf(fmaxf(a0.x, a0.y), fmaxf(a0.z, a0.w)));
        m0 = fmaxf(m0, fmaxf(fmaxf(q0.x, q0.y), fmaxf(q0.z, q0.w)));
        m1 = fmaxf(m1, fmaxf(fmaxf(a1.x, a1.y), fmaxf(a1.z, a1.w)));
        m1 = fmaxf(m1, fmaxf(fmaxf(q1.x, q1.y), fmaxf(q1.z, q1.w)));
        if (i == i0) {
            xg[row0 * 2]     = sel8(a0, q0, e0);
            xg[row0 * 2 + 2] = sel8(a1, q1, e0);
        }
        if (i == i1) {
            xg[row0 * 2 + 1] = sel8(a0, q0, e1);
            xg[row0 * 2 + 3] = sel8(a1, q1, e1);
        }
        H8 o0, o1;
        o0.h[0] = __floats2half2_rn(a0.x, a0.y);
        o0.h[1] = __floats2half2_rn(a0.z, a0.w);
        o0.h[2] = __floats2half2_rn(q0.x, q0.y);
        o0.h[3] = __floats2half2_rn(q0.z, q0.w);
        o1.h[0] = __floats2half2_rn(a1.x, a1.y);
        o1.h[1] = __floats2half2_rn(a1.z, a1.w);
        o1.h[2] = __floats2half2_rn(q1.x, q1.y);
        o1.h[3] = __floats2half2_rn(q1.z, q1.w);
        size_t toff = (size_t)(i >> 4) * 32768 + ((i & 15) << 3);
        *(f32x4*)(trow0 + toff) = o0.v;
        *(f32x4*)(trow1 + toff) = o1.v;
    }
    // zero pad chunks (cols 2000..2047 = stripe 15, chunks 10..15)
    if (lane < 6) {
        int i = 250 + lane;
        f32x4 z = {0.f, 0.f, 0.f, 0.f};
        size_t toff = (size_t)15 * 32768 + ((i & 15) << 3);
        *(f32x4*)(trow0 + toff) = z;
        *(f32x4*)(trow1 + toff) = z;
    }
#pragma unroll
    for (int off = 32; off; off >>= 1) {
        m0 = fmaxf(m0, __shfl_xor(m0, off));
        m1 = fmaxf(m1, __shfl_xor(m1, off));
    }
    if (!lane) {
        glb[row0]     = m0;
        glb[row0 + 1] = m1;
    }
}

// -------- K2: prep, wave-per-row coalesced matvecs (r15 best) --------
__global__ __launch_bounds__(256) void k_prep(
    const float* __restrict__ xg, const float* __restrict__ glb,
    const float* __restrict__ Wg, const float* __restrict__ bg,
    const float* __restrict__ Wnode, const float* __restrict__ bnode,
    const float* __restrict__ Wlc, const float* __restrict__ blc,
    float* __restrict__ cK, float* __restrict__ cK0)
{
    int b = blockIdx.x, tid = threadIdx.x, w = tid >> 6, lane = tid & 63;
    __shared__ float s_glb[FF], s_ctx[2 * FF], s_cQ[FF], s_bias[FF], s_red[FF];
    s_glb[tid] = glb[b * FF + tid];
    float2 g2 = ((const float2*)xg)[b * FF + tid];
    s_ctx[tid]      = g2.x;
    s_ctx[FF + tid] = g2.y;
    s_bias[tid] = bg[tid] + blc[tid];
    __syncthreads();

    f32x4 gv  = *(const f32x4*)&s_glb[lane << 2];
    f32x4 c0v = *(const f32x4*)&s_ctx[lane << 3];
    f32x4 c1v = *(const f32x4*)&s_ctx[(lane << 3) + 4];

    for (int k = 0; k < 64; k += 4) {
        float p0, p1, p2, p3;
        {
            int fb = (w << 6) + k;
            f32x4 wg0 = *(const f32x4*)(Wg + (size_t)fb * FF + (lane << 2));
            f32x4 wg1 = *(const f32x4*)(Wg + (size_t)(fb + 1) * FF + (lane << 2));
            f32x4 wg2 = *(const f32x4*)(Wg + (size_t)(fb + 2) * FF + (lane << 2));
            f32x4 wg3 = *(const f32x4*)(Wg + (size_t)(fb + 3) * FF + (lane << 2));
            f32x4 wa0 = *(const f32x4*)(Wlc + (size_t)fb * 2 * FF + (lane << 3));
            f32x4 wb0 = *(const f32x4*)(Wlc + (size_t)fb * 2 * FF + (lane << 3) + 4);
            f32x4 wa1 = *(const f32x4*)(Wlc + (size_t)(fb + 1) * 2 * FF + (lane << 3));
            f32x4 wb1 = *(const f32x4*)(Wlc + (size_t)(fb + 1) * 2 * FF + (lane << 3) + 4);
            f32x4 wa2 = *(const f32x4*)(Wlc + (size_t)(fb + 2) * 2 * FF + (lane << 3));
            f32x4 wb2 = *(const f32x4*)(Wlc + (size_t)(fb + 2) * 2 * FF + (lane << 3) + 4);
            f32x4 wa3 = *(const f32x4*)(Wlc + (size_t)(fb + 3) * 2 * FF + (lane << 3));
            f32x4 wb3 = *(const f32x4*)(Wlc + (size_t)(fb + 3) * 2 * FF + (lane << 3) + 4);
            p0 = dot4(wg0, gv) + dot4(wa0, c0v) + dot4(wb0, c1v);
            p1 = dot4(wg1, gv) + dot4(wa1, c0v) + dot4(wb1, c1v);
            p2 = dot4(wg2, gv) + dot4(wa2, c0v) + dot4(wb2, c1v);
            p3 = dot4(wg3, gv) + dot4(wa3, c0v) + dot4(wb3, c1v);
        }
#pragma unroll
        for (int off = 32; off; off >>= 1) {
            p0 += __shfl_xor(p0, off);
            p1 += __shfl_xor(p1, off);
            p2 += __shfl_xor(p2, off);
            p3 += __shfl_xor(p3, off);
        }
        if (lane == 0) {
            int fb = (w << 6) + k;
            s_cQ[fb]     = p0 + s_bias[fb];
            s_cQ[fb + 1] = p1 + s_bias[fb + 1];
            s_cQ[fb + 2] = p2 + s_bias[fb + 2];
            s_cQ[fb + 3] = p3 + s_bias[fb + 3];
        }
    }
    __syncthreads();

    {
        float a0 = 0, a1 = 0, a2 = 0, a3 = 0, a4 = 0, a5 = 0, a6 = 0, a7 = 0;
        for (int g = 0; g < FF; g += 8) {
            float w0 = Wnode[(size_t)(g + 0) * FF + tid];
            float w1 = Wnode[(size_t)(g + 1) * FF + tid];
            float w2 = Wnode[(size_t)(g + 2) * FF + tid];
            float w3 = Wnode[(size_t)(g + 3) * FF + tid];
            float w4 = Wnode[(size_t)(g + 4) * FF + tid];
            float w5 = Wnode[(size_t)(g + 5) * FF + tid];
            float w6 = Wnode[(size_t)(g + 6) * FF + tid];
            float w7 = Wnode[(size_t)(g + 7) * FF + tid];
            a0 = fmaf(s_cQ[g + 0], w0, a0); a1 = fmaf(s_cQ[g + 1], w1, a1);
            a2 = fmaf(s_cQ[g + 2], w2, a2); a3 = fmaf(s_cQ[g + 3], w3, a3);
            a4 = fmaf(s_cQ[g + 4], w4, a4); a5 = fmaf(s_cQ[g + 5], w5, a5);
            a6 = fmaf(s_cQ[g + 6], w6, a6); a7 = fmaf(s_cQ[g + 7], w7, a7);
        }
        cK[b * FF + tid] = ((a0 + a1) + (a2 + a3)) + ((a4 + a5) + (a6 + a7));
    }
    s_red[tid] = s_cQ[tid] * bnode[tid];
    __syncthreads();
    for (int s = 128; s > 0; s >>= 1) {
        if (tid < s) s_red[tid] += s_red[tid + s];
        __syncthreads();
    }
    if (tid == 0) cK0[b] = s_red[0];
}

// -------- K3: fused attn, register tile over TILED xh; loads issued FIRST --------
__global__ __launch_bounds__(512) void k_attn(
    const __half* __restrict__ xh,
    const float* __restrict__ cK, const float* __restrict__ cK0,
    float* __restrict__ y_part, float* __restrict__ m_part,
    float* __restrict__ s_part)
{
    int b = blockIdx.x >> 4, st = blockIdx.x & 15;
    int tid = threadIdx.x, w = tid >> 6, lane = tid & 63;
    int par = lane >> 4, chunk = lane & 15;
    __shared__ float tbuf[8][512];
    __shared__ float s_u[8][SCA];
    __shared__ float s_p[SCA];
    __shared__ float s_cK[FF];
    __shared__ float s_red[8], s_red2[8];

    // issue the 8 bulk loads FIRST (independent of LDS) to hide latency
    const __half* base = xh + ((size_t)((b << 4) + st) * 256 + (w << 5) + par) * 128 + (chunk << 3);
    f32x4 hv[8];
#pragma unroll
    for (int r = 0; r < 8; ++r)
        hv[r] = *(const f32x4*)(base + (size_t)(r << 9));    // r*4 rows * 128 halves

    if (tid < FF) s_cK[tid] = cK[b * FF + tid];
    __syncthreads();

    float uc0 = 0, uc1 = 0, uc2 = 0, uc3 = 0, uc4 = 0, uc5 = 0, uc6 = 0, uc7 = 0;
#pragma unroll
    for (int r = 0; r < 8; ++r) {
        int row = (w << 5) + (r << 2) + par;
        H8 u; u.v = hv[r];
        float c = s_cK[row];
        float2 q0 = __half22float2(u.h[0]);
        float2 q1 = __half22float2(u.h[1]);
        float2 q2 = __half22float2(u.h[2]);
        float2 q3 = __half22float2(u.h[3]);
        uc0 = fmaf(c, q0.x, uc0); uc1 = fmaf(c, q0.y, uc1);
        uc2 = fmaf(c, q1.x, uc2); uc3 = fmaf(c, q1.y, uc3);
        uc4 = fmaf(c, q2.x, uc4); uc5 = fmaf(c, q2.y, uc5);
        uc6 = fmaf(c, q3.x, uc6); uc7 = fmaf(c, q3.y, uc7);
    }
    uc0 += __shfl_xor(uc0, 16); uc0 += __shfl_xor(uc0, 32);
    uc1 += __shfl_xor(uc1, 16); uc1 += __shfl_xor(uc1, 32);
    uc2 += __shfl_xor(uc2, 16); uc2 += __shfl_xor(uc2, 32);
    uc3 += __shfl_xor(uc3, 16); uc3 += __shfl_xor(uc3, 32);
    uc4 += __shfl_xor(uc4, 16); uc4 += __shfl_xor(uc4, 32);
    uc5 += __shfl_xor(uc5, 16); uc5 += __shfl_xor(uc5, 32);
    uc6 += __shfl_xor(uc6, 16); uc6 += __shfl_xor(uc6, 32);
    uc7 += __shfl_xor(uc7, 16); uc7 += __shfl_xor(uc7, 32);
    if (par == 0) {
        f32x4 v0 = {uc0, uc1, uc2, uc3}, v1 = {uc4, uc5, uc6, uc7};
        *(f32x4*)&s_u[w][chunk << 3]       = v0;
        *(f32x4*)&s_u[w][(chunk << 3) + 4] = v1;
    }
    __syncthreads();

    const float scale = 0.0625f;
    float uu = -INFINITY;
    if (tid < SCA) {
        int col = (st << 7) + tid;
        if (col < NN) {
            float usum = 0.f;
#pragma unroll
            for (int ww = 0; ww < 8; ++ww) usum += s_u[ww][tid];
            uu = (usum + cK0[b]) * scale;
        }
    }
    float m = uu;
#pragma unroll
    for (int off = 32; off; off >>= 1) m = fmaxf(m, __shfl_xor(m, off));
    if (!lane && w < 2) s_red[w] = m;
    __syncthreads();
    float M = fmaxf(s_red[0], s_red[1]);
    float e = (uu > -INFINITY) ? __expf(uu - M) : 0.f;
    if (tid < SCA) s_p[tid] = e;
    float ssum = e;
#pragma unroll
    for (int off = 32; off; off >>= 1) ssum += __shfl_xor(ssum, off);
    if (!lane && w < 2) s_red2[w] = ssum;
    __syncthreads();
    if (!tid) {
        m_part[(b << 4) + st] = M;
        s_part[(b << 4) + st] = s_red2[0] + s_red2[1];
    }

    f32x4 pv0 = *(const f32x4*)&s_p[chunk << 3];
    f32x4 pv1 = *(const f32x4*)&s_p[(chunk << 3) + 4];
#pragma unroll
    for (int r = 0; r < 8; ++r) {
        H8 u; u.v = hv[r];
        float2 q0 = __half22float2(u.h[0]);
        float2 q1 = __half22float2(u.h[1]);
        float2 q2 = __half22float2(u.h[2]);
        float2 q3 = __half22float2(u.h[3]);
        float a = 0.f;
        a = fmaf(pv0.x, q0.x, a); a = fmaf(pv0.y, q0.y, a);
        a = fmaf(pv0.z, q1.x, a); a = fmaf(pv0.w, q1.y, a);
        a = fmaf(pv1.x, q2.x, a); a = fmaf(pv1.y, q2.y, a);
        a = fmaf(pv1.z, q3.x, a); a = fmaf(pv1.w, q3.y, a);
        tbuf[w][(((r << 2) + par) << 4) + chunk] = a;
    }
    {
        int row = tid >> 1, half = tid & 1;
        const float* srcp = &tbuf[row >> 5][((row & 31) << 4) + (half << 3)];
        f32x4 a0 = *(const f32x4*)srcp;
        f32x4 a1 = *(const f32x4*)(srcp + 4);
        float sm = ((a0.x + a0.y) + (a0.z + a0.w)) + ((a1.x + a1.y) + (a1.z + a1.w));
        sm += __shfl_xor(sm, 1);
        if (!half) y_part[(size_t)((b << 4) + st) * FF + row] = sm;
    }
}

// -------- K4: combine 16 stripe partials -> y -> dense chain (r15 best) --------
__global__ __launch_bounds__(256) void k_dense(
    const float* __restrict__ y_part, const float* __restrict__ m_part,
    const float* __restrict__ s_part,
    const float* __restrict__ Wnode, const float* __restrict__ bnode,
    const float* __restrict__ Wproj, const float* __restrict__ bproj,
    float* __restrict__ cL, float* __restrict__ cL0)
{
    int b = blockIdx.x, tid = threadIdx.x, w = tid >> 6, lane = tid & 63;
    __shared__ float s_y[FF], s_v[FF], s_n[FF], s_b1[FF], s_b2[FF], s_red[FF];

    s_b1[tid] = bnode[FF + tid];
    s_b2[tid] = bproj[tid];
    float M = -INFINITY;
#pragma unroll
    for (int s = 0; s < 16; ++s) M = fmaxf(M, m_part[(b << 4) + s]);
    float S = 0.f, wgt[16];
#pragma unroll
    for (int s = 0; s < 16; ++s) {
        wgt[s] = __expf(m_part[(b << 4) + s] - M);
        S = fmaf(wgt[s], s_part[(b << 4) + s], S);
    }
    float invS = 1.0f / S;
    float acc = 0.f;
#pragma unroll
    for (int s = 0; s < 16; ++s)
        acc = fmaf(wgt[s], y_part[(size_t)((b << 4) + s) * FF + tid], acc);
    s_y[tid] = acc * invS;
    __syncthreads();

    {
        f32x4 yv = *(const f32x4*)&s_y[lane << 2];
        for (int k = 0; k < 64; k += 4) {
            int fb = (w << 6) + k;
            f32x4 w0 = *(const f32x4*)(Wnode + (size_t)(FF + fb) * FF + (lane << 2));
            f32x4 w1 = *(const f32x4*)(Wnode + (size_t)(FF + fb + 1) * FF + (lane << 2));
            f32x4 w2 = *(const f32x4*)(Wnode + (size_t)(FF + fb + 2) * FF + (lane << 2));
            f32x4 w3 = *(const f32x4*)(Wnode + (size_t)(FF + fb + 3) * FF + (lane << 2));
            float p0 = dot4(w0, yv), p1 = dot4(w1, yv), p2 = dot4(w2, yv), p3 = dot4(w3, yv);
#pragma unroll
            for (int off = 32; off; off >>= 1) {
                p0 += __shfl_xor(p0, off);
                p1 += __shfl_xor(p1, off);
                p2 += __shfl_xor(p2, off);
                p3 += __shfl_xor(p3, off);
            }
            if (lane == 0) {
                s_v[fb]     = p0 + s_b1[fb];
                s_v[fb + 1] = p1 + s_b1[fb + 1];
                s_v[fb + 2] = p2 + s_b1[fb + 2];
                s_v[fb + 3] = p3 + s_b1[fb + 3];
            }
        }
    }
    __syncthreads();
    {
        f32x4 vv = *(const f32x4*)&s_v[lane << 2];
        for (int k = 0; k < 64; k += 4) {
            int fb = (w << 6) + k;
            f32x4 w0 = *(const f32x4*)(Wproj + (size_t)fb * FF + (lane << 2));
            f32x4 w1 = *(const f32x4*)(Wproj + (size_t)(fb + 1) * FF + (lane << 2));
            f32x4 w2 = *(const f32x4*)(Wproj + (size_t)(fb + 2) * FF + (lane << 2));
            f32x4 w3 = *(const f32x4*)(Wproj + (size_t)(fb + 3) * FF + (lane << 2));
            float p0 = dot4(w0, vv), p1 = dot4(w1, vv), p2 = dot4(w2, vv), p3 = dot4(w3, vv);
#pragma unroll
            for (int off = 32; off; off >>= 1) {
                p0 += __shfl_xor(p0, off);
                p1 += __shfl_xor(p1, off);
                p2 += __shfl_xor(p2, off);
                p3 += __shfl_xor(p3, off);
            }
            if (lane == 0) {
                s_n[fb]     = p0 + s_b2[fb];
                s_n[fb + 1] = p1 + s_b2[fb + 1];
                s_n[fb + 2] = p2 + s_b2[fb + 2];
                s_n[fb + 3] = p3 + s_b2[fb + 3];
            }
        }
    }
    __syncthreads();
    {
        float a0 = 0, a1 = 0, a2 = 0, a3 = 0, a4 = 0, a5 = 0, a6 = 0, a7 = 0;
        for (int g = 0; g < FF; g += 8) {
            float w0 = Wnode[(size_t)(2 * FF + g + 0) * FF + tid];
            float w1 = Wnode[(size_t)(2 * FF + g + 1) * FF + tid];
            float w2 = Wnode[(size_t)(2 * FF + g + 2) * FF + tid];
            float w3 = Wnode[(size_t)(2 * FF + g + 3) * FF + tid];
            float w4 = Wnode[(size_t)(2 * FF + g + 4) * FF + tid];
            float w5 = Wnode[(size_t)(2 * FF + g + 5) * FF + tid];
            float w6 = Wnode[(size_t)(2 * FF + g + 6) * FF + tid];
            float w7 = Wnode[(size_t)(2 * FF + g + 7) * FF + tid];
            a0 = fmaf(s_n[g + 0], w0, a0); a1 = fmaf(s_n[g + 1], w1, a1);
            a2 = fmaf(s_n[g + 2], w2, a2); a3 = fmaf(s_n[g + 3], w3, a3);
            a4 = fmaf(s_n[g + 4], w4, a4); a5 = fmaf(s_n[g + 5], w5, a5);
            a6 = fmaf(s_n[g + 6], w6, a6); a7 = fmaf(s_n[g + 7], w7, a7);
        }
        cL[b * FF + tid] = ((a0 + a1) + (a2 + a3)) + ((a4 + a5) + (a6 + a7));
    }
    s_red[tid] = s_n[tid] * bnode[2 * FF + tid];
    __syncthreads();
    for (int s = 128; s > 0; s >>= 1) {
        if (tid < s) s_red[tid] += s_red[tid + s];
        __syncthreads();
    }
    if (tid == 0) cL0[b] = s_red[0];
}

// -------- K5: logits + tanh, register tile over TILED xh; loads issued FIRST --------
__global__ __launch_bounds__(512) void k_logits(const __half* __restrict__ xh,
                                                const float* __restrict__ cL,
                                                const float* __restrict__ cL0,
                                                float* __restrict__ out)
{
    int b = blockIdx.x >> 4, st = blockIdx.x & 15;
    int tid = threadIdx.x, w = tid >> 6, lane = tid & 63;
    int par = lane >> 4, chunk = lane & 15;
    __shared__ float s_cL[FF];
    __shared__ float s_acc[8][SCA];

    const __half* base = xh + ((size_t)((b << 4) + st) * 256 + (w << 5) + par) * 128 + (chunk << 3);
    f32x4 hv[8];
#pragma unroll
    for (int r = 0; r < 8; ++r)
        hv[r] = *(const f32x4*)(base + (size_t)(r << 9));

    if (tid < FF) s_cL[tid] = cL[b * FF + tid];
    __syncthreads();

    float uc0 = 0, uc1 = 0, uc2 = 0, uc3 = 0, uc4 = 0, uc5 = 0, uc6 = 0, uc7 = 0;
#pragma unroll
    for (int r = 0; r < 8; ++r) {
        int row = (w << 5) + (r << 2) + par;
        H8 u; u.v = hv[r];
        float c = s_cL[row];
        float2 q0 = __half22float2(u.h[0]);
        float2 q1 = __half22float2(u.h[1]);
        float2 q2 = __half22float2(u.h[2]);
        float2 q3 = __half22float2(u.h[3]);
        uc0 = fmaf(c, q0.x, uc0); uc1 = fmaf(c, q0.y, uc1);
        uc2 = fmaf(c, q1.x, uc2); uc3 = fmaf(c, q1.y, uc3);
        uc4 = fmaf(c, q2.x, uc4); uc5 = fmaf(c, q2.y, uc5);
        uc6 = fmaf(c, q3.x, uc6); uc7 = fmaf(c, q3.y, uc7);
    }
    uc0 += __shfl_xor(uc0, 16); uc0 += __shfl_xor(uc0, 32);
    uc1 += __shfl_xor(uc1, 16); uc1 += __shfl_xor(uc1, 32);
    uc2 += __shfl_xor(uc2, 16); uc2 += __shfl_xor(uc2, 32);
    uc3 += __shfl_xor(uc3, 16); uc3 += __shfl_xor(uc3, 32);
    uc4 += __shfl_xor(uc4, 16); uc4 += __shfl_xor(uc4, 32);
    uc5 += __shfl_xor(uc5, 16); uc5 += __shfl_xor(uc5, 32);
    uc6 += __shfl_xor(uc6, 16); uc6 += __shfl_xor(uc6, 32);
    uc7 += __shfl_xor(uc7, 16); uc7 += __shfl_xor(uc7, 32);
    if (par == 0) {
        f32x4 v0 = {uc0, uc1, uc2, uc3}, v1 = {uc4, uc5, uc6, uc7};
        *(f32x4*)&s_acc[w][chunk << 3]       = v0;
        *(f32x4*)&s_acc[w][(chunk << 3) + 4] = v1;
    }
    __syncthreads();
    if (tid < SCA) {
        int col = (st << 7) + tid;
        if (col < NN) {
            float t = 0.f;
#pragma unroll
            for (int ww = 0; ww < 8; ++ww) t += s_acc[ww][tid];
            out[(size_t)b * NN + col] = tanhf((t + cL0[b]) * 0.0625f) * 10.f;
        }
    }
}

extern "C" void kernel_launch(void* const* d_in, const int* in_sizes, int n_in,
                              void* d_out, int out_size, void* d_ws, size_t ws_size,
                              hipStream_t stream) {
    const float* x     = (const float*)d_in[0];
    const int*   lc    = (const int*)d_in[1];
    const float* Wg    = (const float*)d_in[2];
    const float* bg    = (const float*)d_in[3];
    const float* Wnode = (const float*)d_in[4];
    const float* bnode = (const float*)d_in[5];
    const float* Wlc   = (const float*)d_in[6];
    const float* blc   = (const float*)d_in[7];
    const float* Wproj = (const float*)d_in[8];
    const float* bproj = (const float*)d_in[9];
    float* out = (float*)d_out;

    float* ws     = (float*)d_ws;
    float* glb    = ws + 0;          // B*F
    float* xg     = ws + 32768;      // B*F*2
    float* cK     = ws + 98304;      // B*F
    float* cK0    = ws + 131072;     // B
    float* m_part = ws + 132096;     // B*16
    float* s_part = ws + 134144;     // B*16
    float* cL     = ws + 136192;     // B*F
    float* cL0    = ws + 168960;     // B
    float* y_part = ws + 169984;     // B*16*F
    __half* xh    = (__half*)(ws + (2 << 20));  // tiled, 128 MB at 8 MB offset

    k_convmax<<<BB * FF / 8, 256, 0, stream>>>(x, lc, xh, glb, xg);
    k_prep   <<<BB, 256, 0, stream>>>(xg, glb, Wg, bg, Wnode, bnode, Wlc, blc, cK, cK0);
    k_attn   <<<BB * SWA, 512, 0, stream>>>(xh, cK, cK0, y_part, m_part, s_part);
    k_dense  <<<BB, 256, 0, stream>>>(y_part, m_part, s_part, Wnode, bnode, Wproj, bproj, cL, cL0);
    k_logits <<<BB * SWA, 512, 0, stream>>>(xh, cL, cL0, out);
}